// Round 14
// baseline (243.550 us; speedup 1.0000x reference)
//
#include <hip/hip_runtime.h>
#include <stdint.h>

#define ET 128
#define ES 16
#define NF 34   // partial fields: 0=sum_w 1=sum_kl 2..17=t_counts 18..33=s_counts

__host__ __device__ inline uint32_t rotl32(uint32_t x, int r) {
#ifdef __HIP_DEVICE_COMPILE__
  return __builtin_amdgcn_alignbit(x, x, (uint32_t)(32 - r));  // 1 instr
#else
  return (x << r) | (x >> (32 - r));
#endif
}

__host__ __device__ inline void tf2x32(uint32_t k0, uint32_t k1,
                                       uint32_t& x0, uint32_t& x1) {
  uint32_t ks2 = k0 ^ k1 ^ 0x1BD11BDAu;
  x0 += k0; x1 += k1;
#define TF_ROT(r) { x0 += x1; x1 = rotl32(x1, r); x1 ^= x0; }
  TF_ROT(13) TF_ROT(15) TF_ROT(26) TF_ROT(6)
  x0 += k1;  x1 += ks2 + 1u;
  TF_ROT(17) TF_ROT(29) TF_ROT(16) TF_ROT(24)
  x0 += ks2; x1 += k0 + 2u;
  TF_ROT(13) TF_ROT(15) TF_ROT(26) TF_ROT(6)
  x0 += k0;  x1 += k1 + 3u;
  TF_ROT(17) TF_ROT(29) TF_ROT(16) TF_ROT(24)
  x0 += k1;  x1 += ks2 + 4u;
  TF_ROT(13) TF_ROT(15) TF_ROT(26) TF_ROT(6)
  x0 += ks2; x1 += k0 + 5u;
#undef TF_ROT
}

// partitionable threefry uniform for flat index j; u = f-1 in [0,1).
// (JAX's TINY add/clamp is identity for u>0; u==0 -> e=+inf, never wins.)
__device__ inline float unif01m(uint32_t s0, uint32_t s1, uint32_t j) {
  uint32_t x0 = 0u, x1 = j;
  tf2x32(s0, s1, x0, x1);
  uint32_t bits = x0 ^ x1;
  return __uint_as_float((bits >> 9) | 0x3F800000u) - 1.0f;
}

__device__ inline float fastrcp(float x) { return __builtin_amdgcn_rcpf(x); }

template <int CTRL>
__device__ inline uint32_t dpp32(uint32_t v) {
  return (uint32_t)__builtin_amdgcn_update_dpp((int)v, (int)v, CTRL, 0xF, 0xF,
                                               false);
}

// 16 lanes/token, 8 experts/lane, 4 tokens/wave, single fused kernel.
// Winner = argmin_e( -log(u_e)/p_e ) (exponential race == gumbel argmax).
// u32 score key with expert idx packed in the low 7 mantissa bits.
// Accumulation: store-based per-block partials (no zero-init required) +
// modulo done-counter (start-value-agnostic: exactly one block of each call
// sees (prev+1) % G == 0, G power of 2) + __threadfence() (device-scope,
// covers cross-XCD per G16) + plain pipelined loads in the last-block reduce.
// NOTE: no min-waves launch-bounds arg (R11: forcing 8/EU -> VGPR 32 ->
// full spill -> 10x regression).
__launch_bounds__(256)
__global__ void sample_kernel(const float* __restrict__ tg,
                              const float* __restrict__ sg,
                              const int* __restrict__ am,
                              double* __restrict__ acc,
                              unsigned int* __restrict__ done,
                              float* __restrict__ out,
                              uint32_t s00, uint32_t s01,
                              uint32_t s10, uint32_t s11,
                              uint32_t s20, uint32_t s21,
                              int N, int total_waves) {
  __shared__ float lds_t[ES], lds_s[ES];
  __shared__ float lds_w[4], lds_kl[4];
  __shared__ int lds_last;
  __shared__ double tot[NF];
  if (threadIdx.x < ES) { lds_t[threadIdx.x] = 0.f; lds_s[threadIdx.x] = 0.f; }
  __syncthreads();

  const int wslot = threadIdx.x >> 6;
  const int wid = blockIdx.x * 4 + wslot;
  const int lane = threadIdx.x & 63;
  const int gl = lane & 15;
  const int gbase = lane & 0x30;
  const int stride = total_waves * 4;
  const float NLN2 = -0.69314718055994530942f;

  float sum_w = 0.f, sum_kl = 0.f;

#define STEP(KA, KB, LAST)                                                   \
  {                                                                          \
    float e[8];                                                              \
    _Pragma("unroll")                                                        \
    for (int q = 0; q < 8; ++q)                                              \
      e[q] = __log2f(unif01m(KA, KB, jb + (uint32_t)q)) * invn[q];           \
    uint32_t key = 0xFFFFFFFFu;                                              \
    _Pragma("unroll")                                                        \
    for (int q = 0; q < 8; ++q) {                                            \
      uint32_t kq = (__float_as_uint(e[q]) & 0xFFFFFF80u)                    \
                    | (uint32_t)(ebase + q);                                 \
      key = (kq < key) ? kq : key;                                           \
    }                                                                        \
    { uint32_t o;                                                            \
      o = dpp32<0x128>(key); key = (o < key) ? o : key;                      \
      o = dpp32<0x124>(key); key = (o < key) ? o : key;                      \
      o = dpp32<0x122>(key); key = (o < key) ? o : key;                      \
      o = dpp32<0x121>(key); key = (o < key) ? o : key;                      \
    }                                                                        \
    const int bi = (int)(key & 0x7Fu);                                       \
    const int wl = bi >> 3, wslt = bi & 7;                                   \
    float pw = p[0];                                                         \
    _Pragma("unroll")                                                        \
    for (int q = 1; q < 8; ++q) pw = (wslt == q) ? p[q] : pw;                \
    float w_abs = __shfl(pw, gbase | wl);                                    \
    float sgkl = __shfl(sgv, gbase | wl);                                    \
    float sgcv = __shfl(sgv, gbase | (bi & 15));                             \
    float wsv = w_abs * fastrcp(t) * vm;                                     \
    const bool lead = (gl == 0);                                             \
    sum_w += lead ? wsv : 0.f;                                               \
    float klt = (wslt == 0) ? (-__logf(sgkl)) * wsv : 0.f;                   \
    sum_kl += lead ? klt : 0.f;                                              \
    if (lead && bi < ES) {                                                   \
      atomicAdd(&lds_t[bi], wsv);                                            \
      atomicAdd(&lds_s[bi], sgcv * vm);                                      \
    }                                                                        \
    if (!(LAST)) {                                                           \
      const bool mt = (gl == wl);                                            \
      _Pragma("unroll")                                                      \
      for (int q = 0; q < 8; ++q) {                                          \
        bool hit = mt && (wslt == q);                                        \
        p[q] = hit ? p[q] * 0.5f : p[q];                                     \
        invn[q] = hit ? invn[q] * 2.0f : invn[q];                            \
      }                                                                      \
      t -= 0.5f * w_abs;                                                     \
    }                                                                        \
  }

  for (int base = wid * 4; base < N; base += stride) {
    const int nr = base + (lane >> 4);
    const int ok = (nr < N);
    const int n = ok ? nr : (N - 1);

    const float4* r4 = (const float4*)(tg + (size_t)n * ET + gl * 8);
    float4 aa = r4[0], bb = r4[1];
    float p[8] = {aa.x, aa.y, aa.z, aa.w, bb.x, bb.y, bb.z, bb.w};
    float sgv = sg[(size_t)n * ES + gl];
    float vm = ok ? (float)am[n] : 0.f;

    float invn[8];
#pragma unroll
    for (int q = 0; q < 8; ++q) invn[q] = NLN2 * fastrcp(p[q]);

    float t = 1.0f;
    const uint32_t jb = (uint32_t)n * ET + (uint32_t)(gl * 8);
    const int ebase = gl * 8;
    STEP(s00, s01, 0)
    STEP(s10, s11, 0)
    STEP(s20, s21, 1)
  }
#undef STEP

#pragma unroll
  for (int off = 32; off; off >>= 1) {
    sum_w += __shfl_xor(sum_w, off);
    sum_kl += __shfl_xor(sum_kl, off);
  }
  if (lane == 0) { lds_w[wslot] = sum_w; lds_kl[wslot] = sum_kl; }
  __syncthreads();

  // per-block partials: plain overwrite stores (no zero-init needed)
  const int G = gridDim.x;
  const int b = blockIdx.x;
  if (threadIdx.x == 0) {
    acc[0 * (size_t)G + b] =
        (double)(lds_w[0] + lds_w[1] + lds_w[2] + lds_w[3]);
    acc[1 * (size_t)G + b] =
        (double)(lds_kl[0] + lds_kl[1] + lds_kl[2] + lds_kl[3]);
  }
  if (threadIdx.x < ES) {
    acc[(size_t)(2 + threadIdx.x) * G + b] = (double)lds_t[threadIdx.x];
    acc[(size_t)(2 + ES + threadIdx.x) * G + b] = (double)lds_s[threadIdx.x];
  }

  // release partials device-wide (covers cross-XCD), then count this block.
  __threadfence();
  if (threadIdx.x == 0) {
    unsigned prev = atomicAdd(done, 1u);   // device-scope by default
    // start-value-agnostic last-block test: exactly one of the G consecutive
    // post-increment values is ≡ 0 (mod G); G is a power of two.
    lds_last = (((prev + 1u) & (unsigned)(G - 1)) == 0u) ? 1 : 0;
  }
  __syncthreads();
  if (!lds_last) return;

  // acquire side: device-scope fence before reading other blocks' partials.
  __threadfence();

  const int tid = threadIdx.x;
  {
    const int w = tid >> 6;        // 4 waves: fields round-robin over waves
    const int l = tid & 63;
    for (int f = w; f < NF; f += 4) {
      const double* src = acc + (size_t)f * G;
      double s = 0.0;
      for (int j = l; j < G; j += 64) s += src[j];   // independent loads
#pragma unroll
      for (int off = 32; off; off >>= 1) s += __shfl_xor(s, off);
      if (l == 0) tot[f] = s;
    }
  }
  __syncthreads();
  if (tid >= 64) return;

  const double EPSD = 1e-8;
  double tv = (tid < ES) ? tot[2 + tid] : 0.0;
  double sv = (tid < ES) ? tot[2 + ES + tid] : 0.0;
  double tsum = tv, ssum = sv;
#pragma unroll
  for (int off = 8; off; off >>= 1) {
    tsum += __shfl_xor(tsum, off);
    ssum += __shfl_xor(ssum, off);
  }
  double ta = tv / tsum + EPSD;
  double sa = sv / ssum + EPSD;
  double ta2 = (tid < ES) ? ta : 0.0;
  double sa2 = (tid < ES) ? sa : 0.0;
#pragma unroll
  for (int off = 8; off; off >>= 1) {
    ta2 += __shfl_xor(ta2, off);
    sa2 += __shfl_xor(sa2, off);
  }
  ta2 += (double)(ET - ES) * EPSD;   // 112 zero bins contribute EPS each
  sa2 += (double)(ET - ES) * EPSD;
  double tn = ta / ta2, sn = sa / sa2;
  double ci = (tid < ES) ? tn * (log(tn) - log(sn)) : 0.0;
#pragma unroll
  for (int off = 8; off; off >>= 1) ci += __shfl_xor(ci, off);

  if (tid == 0) {
    double ta0 = EPSD / ta2, sa0 = EPSD / sa2;
    double cov = ci + (double)(ET - ES) * ta0 * (log(ta0) - log(sa0));
    cov /= (double)ET;
    double feat = tot[1] / fmax(tot[0], EPSD);
    out[0] = (float)(feat + 0.5 * cov);
  }
}

extern "C" void kernel_launch(void* const* d_in, const int* in_sizes, int n_in,
                              void* d_out, int out_size, void* d_ws, size_t ws_size,
                              hipStream_t stream) {
  const float* tg = (const float*)d_in[0];
  const float* sg = (const float*)d_in[1];
  const int*   am = (const int*)d_in[4];
  const int N = in_sizes[4];  // B*S tokens

  // key chain: key = jax.random.key(42); per step foldlike split (partitionable)
  uint32_t key0 = 0u, key1 = 42u;
  uint32_t subs[3][2];
  for (int k = 0; k < 3; ++k) {
    uint32_t a0 = 0u, a1 = 0u; tf2x32(key0, key1, a0, a1);  // new key
    uint32_t b0 = 0u, b1 = 1u; tf2x32(key0, key1, b0, b1);  // subkey
    subs[k][0] = b0; subs[k][1] = b1;
    key0 = a0; key1 = a1;
  }

  // power-of-two grid so the modulo done-counter works from any start value
  int want = (N + 15) / 16;
  if (want < 1) want = 1;
  int blocks = 1;
  while (blocks * 2 <= want && blocks < 2048) blocks *= 2;
  const int total_waves = blocks * 4;

  double* acc = (double*)d_ws;
  unsigned int* done = (unsigned int*)(acc + (size_t)NF * blocks);

  sample_kernel<<<blocks, 256, 0, stream>>>(
      tg, sg, am, acc, done, (float*)d_out,
      subs[0][0], subs[0][1], subs[1][0], subs[1][1], subs[2][0], subs[2][1],
      N, total_waves);
}

// Round 15
// 50.007 us; speedup vs baseline: 4.8703x; 4.8703x over previous
//
#include <hip/hip_runtime.h>
#include <stdint.h>

#define ET 128
#define ES 16
#define ACC_STRIDE 258   // doubles per replica slot
#define ACC_USED 34      // [0]=sum_w [1]=sum_klw [2..17]=t_counts [18..33]=s_counts
#define REPL 16

__host__ __device__ inline uint32_t rotl32(uint32_t x, int r) {
#ifdef __HIP_DEVICE_COMPILE__
  return __builtin_amdgcn_alignbit(x, x, (uint32_t)(32 - r));  // 1 instr
#else
  return (x << r) | (x >> (32 - r));
#endif
}

__host__ __device__ inline void tf2x32(uint32_t k0, uint32_t k1,
                                       uint32_t& x0, uint32_t& x1) {
  uint32_t ks2 = k0 ^ k1 ^ 0x1BD11BDAu;
  x0 += k0; x1 += k1;
#define TF_ROT(r) { x0 += x1; x1 = rotl32(x1, r); x1 ^= x0; }
  TF_ROT(13) TF_ROT(15) TF_ROT(26) TF_ROT(6)
  x0 += k1;  x1 += ks2 + 1u;
  TF_ROT(17) TF_ROT(29) TF_ROT(16) TF_ROT(24)
  x0 += ks2; x1 += k0 + 2u;
  TF_ROT(13) TF_ROT(15) TF_ROT(26) TF_ROT(6)
  x0 += k0;  x1 += k1 + 3u;
  TF_ROT(17) TF_ROT(29) TF_ROT(16) TF_ROT(24)
  x0 += k1;  x1 += ks2 + 4u;
  TF_ROT(13) TF_ROT(15) TF_ROT(26) TF_ROT(6)
  x0 += ks2; x1 += k0 + 5u;
#undef TF_ROT
}

// partitionable threefry uniform for flat index j; u = f-1 in [0,1).
// (JAX's TINY add/clamp is identity for u>0; u==0 -> e=+inf, never wins.)
__device__ inline float unif01m(uint32_t s0, uint32_t s1, uint32_t j) {
  uint32_t x0 = 0u, x1 = j;
  tf2x32(s0, s1, x0, x1);
  uint32_t bits = x0 ^ x1;
  return __uint_as_float((bits >> 9) | 0x3F800000u) - 1.0f;
}

__device__ inline float fastrcp(float x) { return __builtin_amdgcn_rcpf(x); }

template <int CTRL>
__device__ inline uint32_t dpp32(uint32_t v) {
  return (uint32_t)__builtin_amdgcn_update_dpp((int)v, (int)v, CTRL, 0xF, 0xF,
                                               false);
}

// 16 lanes/token, 8 experts/lane, 4 tokens/wave, one token-iter per wave.
// Winner = argmin_e( -log(u_e)/p_e ) (exponential race == gumbel argmax).
// Score key: idx packed into the low 7 mantissa bits -> u32 min reduce.
// KNOWN-GOOD STRUCTURE (R10, 50.2us): memset node + f64 atomicAdd into REPL
// slots + fused finalize behind zeroed done counter. Store-based partials /
// field-major layouts (R11/R12/R14) trip a hipcc codegen cliff: VGPR drops
// to 32, the hot loop spills, VALUBusy 90% -> 10%, 5x regression.
__launch_bounds__(256)
__global__ void sample_kernel(const float* __restrict__ tg,
                              const float* __restrict__ sg,
                              const int* __restrict__ am,
                              double* __restrict__ acc,
                              unsigned int* __restrict__ done,
                              float* __restrict__ out,
                              uint32_t s00, uint32_t s01,
                              uint32_t s10, uint32_t s11,
                              uint32_t s20, uint32_t s21,
                              int N, int total_waves) {
  __shared__ float lds_t[ES], lds_s[ES];
  __shared__ float lds_w[4], lds_kl[4];
  __shared__ int lds_last;
  __shared__ double tot[ACC_USED];
  if (threadIdx.x < ES) { lds_t[threadIdx.x] = 0.f; lds_s[threadIdx.x] = 0.f; }
  __syncthreads();

  const int wslot = threadIdx.x >> 6;
  const int wid = blockIdx.x * 4 + wslot;
  const int lane = threadIdx.x & 63;
  const int gl = lane & 15;        // lane within 16-lane token group
  const int gbase = lane & 0x30;   // first lane of this group
  const int stride = total_waves * 4;
  const float NLN2 = -0.69314718055994530942f;

  float sum_w = 0.f, sum_kl = 0.f;

#define STEP(KA, KB, LAST)                                                   \
  {                                                                          \
    float e[8];                                                              \
    _Pragma("unroll")                                                        \
    for (int q = 0; q < 8; ++q)                                              \
      e[q] = __log2f(unif01m(KA, KB, jb + (uint32_t)q)) * invn[q];           \
    uint32_t key = 0xFFFFFFFFu;                                              \
    _Pragma("unroll")                                                        \
    for (int q = 0; q < 8; ++q) {                                            \
      uint32_t kq = (__float_as_uint(e[q]) & 0xFFFFFF80u)                    \
                    | (uint32_t)(ebase + q);                                 \
      key = (kq < key) ? kq : key;                                           \
    }                                                                        \
    { uint32_t o;                                                            \
      o = dpp32<0x128>(key); key = (o < key) ? o : key;                      \
      o = dpp32<0x124>(key); key = (o < key) ? o : key;                      \
      o = dpp32<0x122>(key); key = (o < key) ? o : key;                      \
      o = dpp32<0x121>(key); key = (o < key) ? o : key;                      \
    }                                                                        \
    const int bi = (int)(key & 0x7Fu);                                       \
    const int wl = bi >> 3, wslt = bi & 7;                                   \
    float pw = p[0];                                                         \
    _Pragma("unroll")                                                        \
    for (int q = 1; q < 8; ++q) pw = (wslt == q) ? p[q] : pw;                \
    float w_abs = __shfl(pw, gbase | wl);                                    \
    float sgkl = __shfl(sgv, gbase | wl);                                    \
    float sgcv = __shfl(sgv, gbase | (bi & 15));                             \
    float wsv = w_abs * fastrcp(t) * vm;                                     \
    const bool lead = (gl == 0);                                             \
    sum_w += lead ? wsv : 0.f;                                               \
    float klt = (wslt == 0) ? (-__logf(sgkl)) * wsv : 0.f;                   \
    sum_kl += lead ? klt : 0.f;                                              \
    if (lead && bi < ES) {                                                   \
      atomicAdd(&lds_t[bi], wsv);                                            \
      atomicAdd(&lds_s[bi], sgcv * vm);                                      \
    }                                                                        \
    if (!(LAST)) {                                                           \
      const bool mt = (gl == wl);                                            \
      _Pragma("unroll")                                                      \
      for (int q = 0; q < 8; ++q) {                                          \
        bool hit = mt && (wslt == q);                                        \
        p[q] = hit ? p[q] * 0.5f : p[q];                                     \
        invn[q] = hit ? invn[q] * 2.0f : invn[q];                            \
      }                                                                      \
      t -= 0.5f * w_abs;                                                     \
    }                                                                        \
  }

  for (int base = wid * 4; base < N; base += stride) {
    const int nr = base + (lane >> 4);
    const int ok = (nr < N);
    const int n = ok ? nr : (N - 1);

    const float4* r4 = (const float4*)(tg + (size_t)n * ET + gl * 8);
    float4 aa = r4[0], bb = r4[1];
    float p[8] = {aa.x, aa.y, aa.z, aa.w, bb.x, bb.y, bb.z, bb.w};
    float sgv = sg[(size_t)n * ES + gl];
    float vm = ok ? (float)am[n] : 0.f;

    // e = log2(u) * (-ln2 / p): negative scale folds -ln() into one mul
    float invn[8];
#pragma unroll
    for (int q = 0; q < 8; ++q) invn[q] = NLN2 * fastrcp(p[q]);

    float t = 1.0f;
    const uint32_t jb = (uint32_t)n * ET + (uint32_t)(gl * 8);
    const int ebase = gl * 8;
    STEP(s00, s01, 0)
    STEP(s10, s11, 0)
    STEP(s20, s21, 1)
  }
#undef STEP

#pragma unroll
  for (int off = 32; off; off >>= 1) {
    sum_w += __shfl_xor(sum_w, off);
    sum_kl += __shfl_xor(sum_kl, off);
  }
  if (lane == 0) { lds_w[wslot] = sum_w; lds_kl[wslot] = sum_kl; }
  __syncthreads();

  double* slot = acc + (size_t)(blockIdx.x % REPL) * ACC_STRIDE;
  if (threadIdx.x == 0) {
    atomicAdd(&slot[0], (double)(lds_w[0] + lds_w[1] + lds_w[2] + lds_w[3]));
    atomicAdd(&slot[1], (double)(lds_kl[0] + lds_kl[1] + lds_kl[2] + lds_kl[3]));
  }
  if (threadIdx.x < ES) {
    atomicAdd(&slot[2 + threadIdx.x], (double)lds_t[threadIdx.x]);
    atomicAdd(&slot[2 + ES + threadIdx.x], (double)lds_s[threadIdx.x]);
  }

  // ---- last-block finalize (fused) ----
  if (threadIdx.x == 0) {
    __threadfence();
    unsigned prev = atomicAdd(done, 1u);
    lds_last = (prev == (unsigned)(gridDim.x - 1)) ? 1 : 0;
  }
  __syncthreads();
  if (!lds_last) return;

  const int tid = threadIdx.x;
  if (tid < ACC_USED) {
    double s = 0.0;
    for (int r = 0; r < REPL; ++r)
      s += __hip_atomic_load(&acc[(size_t)r * ACC_STRIDE + tid],
                             __ATOMIC_RELAXED, __HIP_MEMORY_SCOPE_AGENT);
    tot[tid] = s;
  }
  __syncthreads();

  const double EPSD = 1e-8;
  double tv = (tid < ES) ? tot[2 + tid] : 0.0;
  double sv = (tid < ES) ? tot[2 + ES + tid] : 0.0;
  double tsum = tv, ssum = sv;
#pragma unroll
  for (int off = 8; off; off >>= 1) {
    tsum += __shfl_xor(tsum, off);
    ssum += __shfl_xor(ssum, off);
  }
  double ta = tv / tsum + EPSD;
  double sa = sv / ssum + EPSD;
  double ta2 = (tid < ES) ? ta : 0.0;
  double sa2 = (tid < ES) ? sa : 0.0;
#pragma unroll
  for (int off = 8; off; off >>= 1) {
    ta2 += __shfl_xor(ta2, off);
    sa2 += __shfl_xor(sa2, off);
  }
  ta2 += (double)(ET - ES) * EPSD;   // 112 zero bins contribute EPS each
  sa2 += (double)(ET - ES) * EPSD;
  double tn = ta / ta2, sn = sa / sa2;
  double ci = (tid < ES) ? tn * (log(tn) - log(sn)) : 0.0;
#pragma unroll
  for (int off = 8; off; off >>= 1) ci += __shfl_xor(ci, off);

  if (tid == 0) {
    double ta0 = EPSD / ta2, sa0 = EPSD / sa2;
    double cov = ci + (double)(ET - ES) * ta0 * (log(ta0) - log(sa0));
    cov /= (double)ET;
    double feat = tot[1] / fmax(tot[0], EPSD);
    out[0] = (float)(feat + 0.5 * cov);
  }
}

extern "C" void kernel_launch(void* const* d_in, const int* in_sizes, int n_in,
                              void* d_out, int out_size, void* d_ws, size_t ws_size,
                              hipStream_t stream) {
  const float* tg = (const float*)d_in[0];
  const float* sg = (const float*)d_in[1];
  const int*   am = (const int*)d_in[4];
  const int N = in_sizes[4];  // B*S tokens

  // key chain: key = jax.random.key(42); per step foldlike split (partitionable)
  uint32_t key0 = 0u, key1 = 42u;
  uint32_t subs[3][2];
  for (int k = 0; k < 3; ++k) {
    uint32_t a0 = 0u, a1 = 0u; tf2x32(key0, key1, a0, a1);  // new key
    uint32_t b0 = 0u, b1 = 1u; tf2x32(key0, key1, b0, b1);  // subkey
    subs[k][0] = b0; subs[k][1] = b1;
    key0 = a0; key1 = a1;
  }

  double* acc = (double*)d_ws;
  unsigned int* done = (unsigned int*)(acc + (size_t)REPL * ACC_STRIDE);
  hipMemsetAsync(d_ws, 0, (size_t)REPL * ACC_STRIDE * sizeof(double) + 64,
                 stream);

  // one 4-token iteration per wave: fills all 8192 wave slots at N=32768
  int blocks = (N + 15) / 16;
  if (blocks > 2048) blocks = 2048;   // grid-stride fallback for larger N
  if (blocks < 1) blocks = 1;
  const int total_waves = blocks * 4;

  sample_kernel<<<blocks, 256, 0, stream>>>(
      tg, sg, am, acc, done, (float*)d_out,
      subs[0][0], subs[0][1], subs[1][0], subs[1][1], subs[2][0], subs[2][1],
      N, total_waves);
}